// Round 1
// baseline (8422.650 us; speedup 1.0000x reference)
//
#include <hip/hip_runtime.h>
#include <math.h>

#define N_ENT 100000
#define N_USR 50000
#define N_TOT 150000
#define DD 64

// ---------------------------------------------------------------------------
// Per-relation precompute: u_r[k] = sum_j Wk_w[k][j]   * rel[r][j]  (k < 64)
//                          v_r[k] = sum_j Wk_w[64+k][j]* rel[r][j]
//                          c_r    = sum_j Wk_b[j]      * rel[r][j]
// uvr layout: [16][132]: u at 0..63, v at 64..127, c at 128
// ---------------------------------------------------------------------------
__global__ void k_rel(const float* __restrict__ Wk_w, const float* __restrict__ Wk_b,
                      const float* __restrict__ rel, float* __restrict__ uvr) {
    int r = blockIdx.x;   // 16 blocks
    int k = threadIdx.x;  // 128 threads
    const float* rv = rel + r * DD;
    const float* wrow = Wk_w + k * DD;
    float s = 0.f;
    for (int j = 0; j < DD; ++j) s += wrow[j] * rv[j];
    uvr[r * 132 + k] = s;
    if (k == 0) {
        float c = 0.f;
        for (int j = 0; j < DD; ++j) c += Wk_b[j] * rv[j];
        uvr[r * 132 + 128] = c;
    }
}

// ---------------------------------------------------------------------------
// Per-edge logits -> leaky relu -> exp; atomic rowsum. 16 lanes per edge.
// ---------------------------------------------------------------------------
__global__ void k_edge(const float* __restrict__ embed, const int* __restrict__ kg_h,
                       const int* __restrict__ kg_t, const int* __restrict__ kg_r,
                       const float* __restrict__ uvr, float* __restrict__ ex,
                       float* __restrict__ rowsum, int E) {
    int gid = blockIdx.x * blockDim.x + threadIdx.x;
    int e = gid >> 4;
    if (e >= E) return;
    int l = gid & 15;
    int h = kg_h[e], t = kg_t[e], r = kg_r[e];
    float4 t4 = *(const float4*)(embed + (size_t)t * DD + l * 4);
    float4 h4 = *(const float4*)(embed + (size_t)h * DD + l * 4);
    float4 u4 = *(const float4*)(uvr + r * 132 + l * 4);
    float4 v4 = *(const float4*)(uvr + r * 132 + 64 + l * 4);
    float p = t4.x * u4.x + t4.y * u4.y + t4.z * u4.z + t4.w * u4.w
            + h4.x * v4.x + h4.y * v4.y + h4.z * v4.z + h4.w * v4.w;
    p += __shfl_xor(p, 1);
    p += __shfl_xor(p, 2);
    p += __shfl_xor(p, 4);
    p += __shfl_xor(p, 8);
    if (l == 0) {
        float lg = p + uvr[r * 132 + 128];
        lg = lg >= 0.f ? lg : 0.01f * lg;
        // softmax is shift-invariant; logits have |l| << 1 so skip segment-max
        float exv = expf(lg);
        ex[e] = exv;
        atomicAdd(rowsum + h, exv);
    }
}

// attn[e] = ex[e] / rowsum[h[e]]   (in place on ex buffer)
__global__ void k_norm(float* __restrict__ attn, const float* __restrict__ rowsum,
                       const int* __restrict__ kg_h, int E) {
    int e = blockIdx.x * blockDim.x + threadIdx.x;
    if (e >= E) return;
    attn[e] = attn[e] / rowsum[kg_h[e]];
}

// ---------------------------------------------------------------------------
// Generic atomic SpMM: out[row[e]] += val[e] * x[col[e]]  (16 lanes/edge)
// ---------------------------------------------------------------------------
__global__ void k_spmm(const int* __restrict__ rows, const int* __restrict__ cols,
                       const float* __restrict__ vals, const float* __restrict__ x,
                       float* __restrict__ out, int E) {
    int gid = blockIdx.x * blockDim.x + threadIdx.x;
    int e = gid >> 4;
    if (e >= E) return;
    int l = gid & 15;
    int r = rows[e], c = cols[e];
    float w = vals[e];
    float4 xv = *(const float4*)(x + (size_t)c * DD + l * 4);
    float* o = out + (size_t)r * DD + l * 4;
    atomicAdd(o + 0, w * xv.x);
    atomicAdd(o + 1, w * xv.y);
    atomicAdd(o + 2, w * xv.z);
    atomicAdd(o + 3, w * xv.w);
}

// ---------------------------------------------------------------------------
// Fusion gate for entity rows, wave per row, Wa/Wb staged in LDS.
// dual[i] = g*kg[i] + (1-g)*ig[i],  g = sigmoid(kg[i]@Wa + ig[i]@Wb)
// sums[i] += ig[i]
// ---------------------------------------------------------------------------
__global__ __launch_bounds__(256) void k_fusion(const float* __restrict__ kg,
        const float* __restrict__ ig, const float* __restrict__ Wa,
        const float* __restrict__ Wb, float* __restrict__ dual,
        float* __restrict__ sums, int n) {
    __shared__ float sW[2 * DD * DD];
    for (int i = threadIdx.x; i < DD * DD; i += blockDim.x) {
        sW[i] = Wa[i];
        sW[DD * DD + i] = Wb[i];
    }
    __syncthreads();
    int lane = threadIdx.x & 63;
    int wslot = (blockIdx.x * blockDim.x + threadIdx.x) >> 6;
    int nw = (gridDim.x * blockDim.x) >> 6;
    for (int row = wslot; row < n; row += nw) {
        float kv = kg[(size_t)row * DD + lane];
        float cv = ig[(size_t)row * DD + lane];
        float a = 0.f, b = 0.f;
        for (int k = 0; k < DD; ++k) {
            float kk = __shfl(kv, k);
            float ck = __shfl(cv, k);
            a = fmaf(kk, sW[k * DD + lane], a);
            b = fmaf(ck, sW[DD * DD + k * DD + lane], b);
        }
        float g = 1.f / (1.f + expf(-(a + b)));
        dual[(size_t)row * DD + lane] = g * kv + (1.f - g) * cv;
        sums[(size_t)row * DD + lane] += cv;
    }
}

// user rows: dual <- ig, sums += ig
__global__ void k_user(const float* __restrict__ ig, float* __restrict__ dual,
                       float* __restrict__ sums) {
    int i = blockIdx.x * blockDim.x + threadIdx.x;
    if (i >= N_USR * DD) return;
    size_t off = (size_t)N_ENT * DD + i;
    float v = ig[off];
    dual[off] = v;
    sums[off] += v;
}

// init: sums = dual = embed; curA = embed[:N_ENT]
__global__ void k_init(const float* __restrict__ embed, float* __restrict__ sums,
                       float* __restrict__ dual, float* __restrict__ curA) {
    int i = blockIdx.x * blockDim.x + threadIdx.x;
    if (i >= N_TOT * DD) return;
    float v = embed[i];
    sums[i] = v;
    dual[i] = v;
    if (i < N_ENT * DD) curA[i] = v;
}

// out[u,j] = sums[user_ids[u]] . sums[item_ids[j]];  8 users per block
__global__ __launch_bounds__(256) void k_out(const float* __restrict__ sums,
        const int* __restrict__ user_ids, const int* __restrict__ item_ids,
        float* __restrict__ out) {
    __shared__ float uvec[8 * DD];
    int ub = blockIdx.x * 8;  // 128 blocks
    for (int i = threadIdx.x; i < 8 * DD; i += blockDim.x) {
        int uu = i >> 6, d = i & 63;
        uvec[i] = sums[(size_t)user_ids[ub + uu] * DD + d];
    }
    __syncthreads();
    for (int j = threadIdx.x; j < 2048; j += blockDim.x) {
        const float* irow = sums + (size_t)item_ids[j] * DD;
        float acc[8] = {0.f, 0.f, 0.f, 0.f, 0.f, 0.f, 0.f, 0.f};
        for (int d = 0; d < DD; d += 4) {
            float4 iv = *(const float4*)(irow + d);
#pragma unroll
            for (int u = 0; u < 8; ++u) {
                acc[u] = fmaf(iv.x, uvec[u * DD + d + 0], acc[u]);
                acc[u] = fmaf(iv.y, uvec[u * DD + d + 1], acc[u]);
                acc[u] = fmaf(iv.z, uvec[u * DD + d + 2], acc[u]);
                acc[u] = fmaf(iv.w, uvec[u * DD + d + 3], acc[u]);
            }
        }
#pragma unroll
        for (int u = 0; u < 8; ++u) out[(size_t)(ub + u) * 2048 + j] = acc[u];
    }
}

extern "C" void kernel_launch(void* const* d_in, const int* in_sizes, int n_in,
                              void* d_out, int out_size, void* d_ws, size_t ws_size,
                              hipStream_t stream) {
    const float* embed   = (const float*)d_in[0];
    const float* rel     = (const float*)d_in[1];
    const float* Wk_w    = (const float*)d_in[2];
    const float* Wk_b    = (const float*)d_in[3];
    const float* Wa      = (const float*)d_in[4];
    const float* Wb      = (const float*)d_in[5];
    const int*   kg_h    = (const int*)d_in[6];
    const int*   kg_t    = (const int*)d_in[7];
    const int*   kg_r    = (const int*)d_in[8];
    const int*   ain_row = (const int*)d_in[9];
    const int*   ain_col = (const int*)d_in[10];
    const float* ain_val = (const float*)d_in[11];
    const int*   user_ids = (const int*)d_in[12];
    const int*   item_ids = (const int*)d_in[13];
    int E_KG = in_sizes[6];
    int E_CF = in_sizes[9];
    float* out = (float*)d_out;

    float* ws = (float*)d_ws;
    size_t off = 0;
    float* uvr    = ws + off; off += 16 * 132;            // 2112 floats (16B aligned after)
    float* attn   = ws + off; off += (size_t)E_KG;        // ex, then attn in place
    float* rowsum = ws + off; off += N_ENT;
    float* bufA   = ws + off; off += (size_t)N_ENT * DD;
    float* bufB   = ws + off; off += (size_t)N_ENT * DD;
    float* dual   = ws + off; off += (size_t)N_TOT * DD;
    float* igout  = ws + off; off += (size_t)N_TOT * DD;
    float* sums   = ws + off; off += (size_t)N_TOT * DD;

    // --- attention (once) ---
    hipLaunchKernelGGL(k_rel, dim3(16), dim3(128), 0, stream, Wk_w, Wk_b, rel, uvr);
    hipMemsetAsync(rowsum, 0, (size_t)N_ENT * sizeof(float), stream);
    {
        long long th = (long long)E_KG * 16;
        int blocks = (int)((th + 255) / 256);
        hipLaunchKernelGGL(k_edge, dim3(blocks), dim3(256), 0, stream,
                           embed, kg_h, kg_t, kg_r, uvr, attn, rowsum, E_KG);
    }
    hipLaunchKernelGGL(k_norm, dim3((E_KG + 255) / 256), dim3(256), 0, stream,
                       attn, rowsum, kg_h, E_KG);
    hipLaunchKernelGGL(k_init, dim3((N_TOT * DD + 255) / 256), dim3(256), 0, stream,
                       embed, sums, dual, bufA);

    // --- 3 propagation layers (host-unrolled, ping-pong cur/kgout) ---
    float* cur = bufA;
    float* kgout = bufB;
    for (int layer = 0; layer < 3; ++layer) {
        hipMemsetAsync(kgout, 0, (size_t)N_ENT * DD * sizeof(float), stream);
        {
            long long th = (long long)E_KG * 16;
            int blocks = (int)((th + 255) / 256);
            hipLaunchKernelGGL(k_spmm, dim3(blocks), dim3(256), 0, stream,
                               kg_h, kg_t, attn, cur, kgout, E_KG);
        }
        hipMemsetAsync(igout, 0, (size_t)N_TOT * DD * sizeof(float), stream);
        {
            long long th = (long long)E_CF * 16;
            int blocks = (int)((th + 255) / 256);
            hipLaunchKernelGGL(k_spmm, dim3(blocks), dim3(256), 0, stream,
                               ain_row, ain_col, ain_val, dual, igout, E_CF);
        }
        hipLaunchKernelGGL(k_fusion, dim3(2048), dim3(256), 0, stream,
                           kgout, igout, Wa, Wb, dual, sums, N_ENT);
        hipLaunchKernelGGL(k_user, dim3((N_USR * DD + 255) / 256), dim3(256), 0, stream,
                           igout, dual, sums);
        float* tmp = cur; cur = kgout; kgout = tmp;
    }

    // --- final gather-GEMM 1024 x 2048 x 64 ---
    hipLaunchKernelGGL(k_out, dim3(128), dim3(256), 0, stream, sums, user_ids, item_ids, out);
}

// Round 2
// 2085.659 us; speedup vs baseline: 4.0384x; 4.0384x over previous
//
#include <hip/hip_runtime.h>
#include <math.h>

#define N_ENT 100000
#define N_USR 50000
#define N_TOT 150000
#define DD 64

// ---------------------------------------------------------------------------
// Per-relation precompute: u_r = Wk_w[0:64]@r, v_r = Wk_w[64:128]@r, c_r = b@r
// uvr layout: [16][132]: u at 0..63, v at 64..127, c at 128
// ---------------------------------------------------------------------------
__global__ void k_rel(const float* __restrict__ Wk_w, const float* __restrict__ Wk_b,
                      const float* __restrict__ rel, float* __restrict__ uvr) {
    int r = blockIdx.x;   // 16 blocks
    int k = threadIdx.x;  // 128 threads
    const float* rv = rel + r * DD;
    const float* wrow = Wk_w + k * DD;
    float s = 0.f;
    for (int j = 0; j < DD; ++j) s += wrow[j] * rv[j];
    uvr[r * 132 + k] = s;
    if (k == 0) {
        float c = 0.f;
        for (int j = 0; j < DD; ++j) c += Wk_b[j] * rv[j];
        uvr[r * 132 + 128] = c;
    }
}

// histogram of row indices
__global__ void k_hist(const int* __restrict__ rows, int* __restrict__ cnt, int E) {
    int e = blockIdx.x * blockDim.x + threadIdx.x;
    if (e < E) atomicAdd(cnt + rows[e], 1);
}

// single-block exclusive scan: cnt[i] (counts) -> rowptr[i]; cnt[i] becomes the
// scatter cursor (== rowptr[i]); rowptr[n] = total.
__global__ __launch_bounds__(1024) void k_scan(int* __restrict__ cnt,
                                               int* __restrict__ rowptr, int n) {
    __shared__ int part[1024];
    int tid = threadIdx.x;
    int chunk = (n + 1023) >> 10;
    int s = tid * chunk; if (s > n) s = n;
    int e = s + chunk;   if (e > n) e = n;
    int sum = 0;
    for (int i = s; i < e; ++i) sum += cnt[i];
    part[tid] = sum;
    __syncthreads();
    for (int off = 1; off < 1024; off <<= 1) {
        int t = (tid >= off) ? part[tid - off] : 0;
        __syncthreads();
        part[tid] += t;
        __syncthreads();
    }
    int run = tid ? part[tid - 1] : 0;
    for (int i = s; i < e; ++i) {
        int c = cnt[i];
        rowptr[i] = run;
        cnt[i] = run;       // scatter cursor
        run += c;
    }
    if (tid == 1023) rowptr[n] = part[1023];
}

// ---------------------------------------------------------------------------
// Per-edge logit -> leaky relu -> exp; lane 0 scatters (col, exp) into CSR slot.
// 16 lanes per edge.
// ---------------------------------------------------------------------------
__global__ void k_edge_scatter(const float* __restrict__ embed,
                               const int* __restrict__ kg_h, const int* __restrict__ kg_t,
                               const int* __restrict__ kg_r, const float* __restrict__ uvr,
                               int* __restrict__ next, int* __restrict__ ecol,
                               float* __restrict__ eval, int E) {
    int gid = blockIdx.x * blockDim.x + threadIdx.x;
    int e = gid >> 4;
    if (e >= E) return;
    int l = gid & 15;
    int h = kg_h[e], t = kg_t[e], r = kg_r[e];
    float4 t4 = *(const float4*)(embed + (size_t)t * DD + l * 4);
    float4 h4 = *(const float4*)(embed + (size_t)h * DD + l * 4);
    float4 u4 = *(const float4*)(uvr + r * 132 + l * 4);
    float4 v4 = *(const float4*)(uvr + r * 132 + 64 + l * 4);
    float p = t4.x * u4.x + t4.y * u4.y + t4.z * u4.z + t4.w * u4.w
            + h4.x * v4.x + h4.y * v4.y + h4.z * v4.z + h4.w * v4.w;
    p += __shfl_xor(p, 1);
    p += __shfl_xor(p, 2);
    p += __shfl_xor(p, 4);
    p += __shfl_xor(p, 8);
    if (l == 0) {
        float lg = p + uvr[r * 132 + 128];
        lg = lg >= 0.f ? lg : 0.01f * lg;
        // softmax is shift-invariant; |logit| << 1 so skip segment-max
        float exv = expf(lg);
        int pos = atomicAdd(next + h, 1);
        ecol[pos] = t;
        eval[pos] = exv;
    }
}

// wave per row: normalize eval segment to sum 1 (segment softmax denominator)
__global__ __launch_bounds__(256) void k_rowdiv(const int* __restrict__ rowptr,
                                                float* __restrict__ eval, int n) {
    int wid = (blockIdx.x * blockDim.x + threadIdx.x) >> 6;
    int lane = threadIdx.x & 63;
    if (wid >= n) return;
    int s = rowptr[wid], e = rowptr[wid + 1];
    float sum = 0.f;
    for (int i = s + lane; i < e; i += 64) sum += eval[i];
    for (int off = 32; off; off >>= 1) sum += __shfl_xor(sum, off);
    if (e > s) {
        float inv = 1.f / sum;
        for (int i = s + lane; i < e; i += 64) eval[i] *= inv;
    }
}

// CF edge scatter: 1 thread per edge
__global__ void k_scatter(const int* __restrict__ rows, const int* __restrict__ cols,
                          const float* __restrict__ vals, int* __restrict__ next,
                          int* __restrict__ ecol, float* __restrict__ eval, int E) {
    int e = blockIdx.x * blockDim.x + threadIdx.x;
    if (e >= E) return;
    int r = rows[e];
    int pos = atomicAdd(next + r, 1);
    ecol[pos] = cols[e];
    eval[pos] = vals[e];
}

// ---------------------------------------------------------------------------
// CSR SpMM, wave per row, lane = dim. One coalesced 256B store per row.
// ---------------------------------------------------------------------------
__global__ __launch_bounds__(256) void k_spmm_csr(const int* __restrict__ rowptr,
        const int* __restrict__ ecol, const float* __restrict__ eval,
        const float* __restrict__ x, float* __restrict__ out, int n) {
    int wid = (blockIdx.x * blockDim.x + threadIdx.x) >> 6;
    int lane = threadIdx.x & 63;
    if (wid >= n) return;
    int w = __builtin_amdgcn_readfirstlane(wid);   // wave-uniform -> s_load meta
    int s = rowptr[w], e = rowptr[w + 1];
    float acc0 = 0.f, acc1 = 0.f;
    int i = s;
    for (; i + 2 <= e; i += 2) {
        int c0 = ecol[i], c1 = ecol[i + 1];
        float w0 = eval[i], w1 = eval[i + 1];
        acc0 = fmaf(w0, x[(size_t)c0 * DD + lane], acc0);
        acc1 = fmaf(w1, x[(size_t)c1 * DD + lane], acc1);
    }
    if (i < e) acc0 = fmaf(eval[i], x[(size_t)ecol[i] * DD + lane], acc0);
    out[(size_t)w * DD + lane] = acc0 + acc1;
}

// ---------------------------------------------------------------------------
// Fusion gate for entity rows, wave per row, Wa/Wb staged in LDS.
// dual[i] = g*kg[i] + (1-g)*ig[i],  g = sigmoid(kg[i]@Wa + ig[i]@Wb); sums += ig
// ---------------------------------------------------------------------------
__global__ __launch_bounds__(256) void k_fusion(const float* __restrict__ kg,
        const float* __restrict__ ig, const float* __restrict__ Wa,
        const float* __restrict__ Wb, float* __restrict__ dual,
        float* __restrict__ sums, int n) {
    __shared__ float sW[2 * DD * DD];
    for (int i = threadIdx.x; i < DD * DD; i += blockDim.x) {
        sW[i] = Wa[i];
        sW[DD * DD + i] = Wb[i];
    }
    __syncthreads();
    int lane = threadIdx.x & 63;
    int wslot = (blockIdx.x * blockDim.x + threadIdx.x) >> 6;
    int nw = (gridDim.x * blockDim.x) >> 6;
    for (int row = wslot; row < n; row += nw) {
        float kv = kg[(size_t)row * DD + lane];
        float cv = ig[(size_t)row * DD + lane];
        float a = 0.f, b = 0.f;
        for (int k = 0; k < DD; ++k) {
            float kk = __shfl(kv, k);
            float ck = __shfl(cv, k);
            a = fmaf(kk, sW[k * DD + lane], a);
            b = fmaf(ck, sW[DD * DD + k * DD + lane], b);
        }
        float g = 1.f / (1.f + expf(-(a + b)));
        dual[(size_t)row * DD + lane] = g * kv + (1.f - g) * cv;
        sums[(size_t)row * DD + lane] += cv;
    }
}

// user rows: dual <- ig, sums += ig
__global__ void k_user(const float* __restrict__ ig, float* __restrict__ dual,
                       float* __restrict__ sums) {
    int i = blockIdx.x * blockDim.x + threadIdx.x;
    if (i >= N_USR * DD) return;
    size_t off = (size_t)N_ENT * DD + i;
    float v = ig[off];
    dual[off] = v;
    sums[off] += v;
}

// init: sums = dual = embed
__global__ void k_init(const float* __restrict__ embed, float* __restrict__ sums,
                       float* __restrict__ dual) {
    int i = blockIdx.x * blockDim.x + threadIdx.x;
    if (i >= N_TOT * DD) return;
    float v = embed[i];
    sums[i] = v;
    dual[i] = v;
}

// out[u,j] = sums[user_ids[u]] . sums[item_ids[j]];  8 users per block
__global__ __launch_bounds__(256) void k_out(const float* __restrict__ sums,
        const int* __restrict__ user_ids, const int* __restrict__ item_ids,
        float* __restrict__ out) {
    __shared__ float uvec[8 * DD];
    int ub = blockIdx.x * 8;  // 128 blocks
    for (int i = threadIdx.x; i < 8 * DD; i += blockDim.x) {
        int uu = i >> 6, d = i & 63;
        uvec[i] = sums[(size_t)user_ids[ub + uu] * DD + d];
    }
    __syncthreads();
    for (int j = threadIdx.x; j < 2048; j += blockDim.x) {
        const float* irow = sums + (size_t)item_ids[j] * DD;
        float acc[8] = {0.f, 0.f, 0.f, 0.f, 0.f, 0.f, 0.f, 0.f};
        for (int d = 0; d < DD; d += 4) {
            float4 iv = *(const float4*)(irow + d);
#pragma unroll
            for (int u = 0; u < 8; ++u) {
                acc[u] = fmaf(iv.x, uvec[u * DD + d + 0], acc[u]);
                acc[u] = fmaf(iv.y, uvec[u * DD + d + 1], acc[u]);
                acc[u] = fmaf(iv.z, uvec[u * DD + d + 2], acc[u]);
                acc[u] = fmaf(iv.w, uvec[u * DD + d + 3], acc[u]);
            }
        }
#pragma unroll
        for (int u = 0; u < 8; ++u) out[(size_t)(ub + u) * 2048 + j] = acc[u];
    }
}

extern "C" void kernel_launch(void* const* d_in, const int* in_sizes, int n_in,
                              void* d_out, int out_size, void* d_ws, size_t ws_size,
                              hipStream_t stream) {
    const float* embed   = (const float*)d_in[0];
    const float* rel     = (const float*)d_in[1];
    const float* Wk_w    = (const float*)d_in[2];
    const float* Wk_b    = (const float*)d_in[3];
    const float* Wa      = (const float*)d_in[4];
    const float* Wb      = (const float*)d_in[5];
    const int*   kg_h    = (const int*)d_in[6];
    const int*   kg_t    = (const int*)d_in[7];
    const int*   kg_r    = (const int*)d_in[8];
    const int*   ain_row = (const int*)d_in[9];
    const int*   ain_col = (const int*)d_in[10];
    const float* ain_val = (const float*)d_in[11];
    const int*   user_ids = (const int*)d_in[12];
    const int*   item_ids = (const int*)d_in[13];
    int E_KG = in_sizes[6];
    int E_CF = in_sizes[9];
    float* out = (float*)d_out;

    float* ws = (float*)d_ws;
    size_t off = 0;
    float* uvr       = ws + off; off += 16 * 132;
    int*   kg_cnt    = (int*)(ws + off); off += N_ENT;       // hist -> scatter cursor
    int*   cf_cnt    = (int*)(ws + off); off += N_TOT;       // adjacent: one memset
    int*   kg_rowptr = (int*)(ws + off); off += N_ENT + 4;
    int*   cf_rowptr = (int*)(ws + off); off += N_TOT + 4;
    int*   kg_ecol   = (int*)(ws + off); off += (size_t)E_KG;
    float* kg_eval   = ws + off; off += (size_t)E_KG;
    int*   cf_ecol   = (int*)(ws + off); off += (size_t)E_CF;
    float* cf_eval   = ws + off; off += (size_t)E_CF;
    float* bufA      = ws + off; off += (size_t)N_ENT * DD;
    float* bufB      = ws + off; off += (size_t)N_ENT * DD;
    float* dual      = ws + off; off += (size_t)N_TOT * DD;
    float* igout     = ws + off; off += (size_t)N_TOT * DD;
    float* sums      = ws + off; off += (size_t)N_TOT * DD;

    // --- CSR build for both graphs ---
    hipMemsetAsync(kg_cnt, 0, (size_t)(N_ENT + N_TOT) * sizeof(int), stream);
    hipLaunchKernelGGL(k_hist, dim3((E_KG + 255) / 256), dim3(256), 0, stream, kg_h, kg_cnt, E_KG);
    hipLaunchKernelGGL(k_hist, dim3((E_CF + 255) / 256), dim3(256), 0, stream, ain_row, cf_cnt, E_CF);
    hipLaunchKernelGGL(k_scan, dim3(1), dim3(1024), 0, stream, kg_cnt, kg_rowptr, N_ENT);
    hipLaunchKernelGGL(k_scan, dim3(1), dim3(1024), 0, stream, cf_cnt, cf_rowptr, N_TOT);
    hipLaunchKernelGGL(k_scatter, dim3((E_CF + 255) / 256), dim3(256), 0, stream,
                       ain_row, ain_col, ain_val, cf_cnt, cf_ecol, cf_eval, E_CF);

    // --- attention (once): logits -> exp -> scatter into CSR -> row-normalize ---
    hipLaunchKernelGGL(k_rel, dim3(16), dim3(128), 0, stream, Wk_w, Wk_b, rel, uvr);
    {
        long long th = (long long)E_KG * 16;
        hipLaunchKernelGGL(k_edge_scatter, dim3((int)((th + 255) / 256)), dim3(256), 0, stream,
                           embed, kg_h, kg_t, kg_r, uvr, kg_cnt, kg_ecol, kg_eval, E_KG);
    }
    hipLaunchKernelGGL(k_rowdiv, dim3((N_ENT * 64 + 255) / 256), dim3(256), 0, stream,
                       kg_rowptr, kg_eval, N_ENT);
    hipLaunchKernelGGL(k_init, dim3((N_TOT * DD + 255) / 256), dim3(256), 0, stream,
                       embed, sums, dual);

    // --- 3 propagation layers; layer0 KG input is embed itself ---
    const float* xk = embed;
    float* kgout = bufA;
    float* kgalt = bufB;
    for (int layer = 0; layer < 3; ++layer) {
        hipLaunchKernelGGL(k_spmm_csr, dim3((N_ENT * 64 + 255) / 256), dim3(256), 0, stream,
                           kg_rowptr, kg_ecol, kg_eval, xk, kgout, N_ENT);
        hipLaunchKernelGGL(k_spmm_csr, dim3((N_TOT * 64 + 255) / 256), dim3(256), 0, stream,
                           cf_rowptr, cf_ecol, cf_eval, dual, igout, N_TOT);
        hipLaunchKernelGGL(k_fusion, dim3(2048), dim3(256), 0, stream,
                           kgout, igout, Wa, Wb, dual, sums, N_ENT);
        hipLaunchKernelGGL(k_user, dim3((N_USR * DD + 255) / 256), dim3(256), 0, stream,
                           igout, dual, sums);
        xk = kgout;
        kgout = kgalt;
        kgalt = (float*)xk;
    }

    // --- final gather-GEMM 1024 x 2048 x 64 ---
    hipLaunchKernelGGL(k_out, dim3(128), dim3(256), 0, stream, sums, user_ids, item_ids, out);
}

// Round 3
// 1562.516 us; speedup vs baseline: 5.3904x; 1.3348x over previous
//
#include <hip/hip_runtime.h>
#include <math.h>

#define N_ENT 100000
#define N_USR 50000
#define N_TOT 150000
#define DD 64

#define SCAN_BLK 256
#define SCAN_ITEMS 1024   // elements per scan block

// ---------------------------------------------------------------------------
// Per-relation precompute: u_r = Wk_w[0:64]@r, v_r = Wk_w[64:128]@r, c_r = b@r
// uvr layout: [16][132]: u at 0..63, v at 64..127, c at 128
// ---------------------------------------------------------------------------
__global__ void k_rel(const float* __restrict__ Wk_w, const float* __restrict__ Wk_b,
                      const float* __restrict__ rel, float* __restrict__ uvr) {
    int r = blockIdx.x;   // 16 blocks
    int k = threadIdx.x;  // 128 threads
    const float* rv = rel + r * DD;
    const float* wrow = Wk_w + k * DD;
    float s = 0.f;
    for (int j = 0; j < DD; ++j) s += wrow[j] * rv[j];
    uvr[r * 132 + k] = s;
    if (k == 0) {
        float c = 0.f;
        for (int j = 0; j < DD; ++j) c += Wk_b[j] * rv[j];
        uvr[r * 132 + 128] = c;
    }
}

// histogram of row indices
__global__ void k_hist(const int* __restrict__ rows, int* __restrict__ cnt, int E) {
    int e = blockIdx.x * blockDim.x + threadIdx.x;
    if (e < E) atomicAdd(cnt + rows[e], 1);
}

// --- multi-block exclusive scan, phase 1: per-chunk partial sums ---
__global__ __launch_bounds__(SCAN_BLK) void k_blocksum(const int* __restrict__ cnt,
                                                       int* __restrict__ bsum, int n) {
    __shared__ int s[SCAN_BLK];
    int base = blockIdx.x * SCAN_ITEMS;
    int sum = 0;
    for (int i = threadIdx.x; i < SCAN_ITEMS; i += SCAN_BLK) {
        int idx = base + i;
        if (idx < n) sum += cnt[idx];
    }
    s[threadIdx.x] = sum;
    __syncthreads();
    for (int off = SCAN_BLK / 2; off; off >>= 1) {
        if (threadIdx.x < off) s[threadIdx.x] += s[threadIdx.x + off];
        __syncthreads();
    }
    if (threadIdx.x == 0) bsum[blockIdx.x] = s[0];
}

// --- phase 2: single-block exclusive scan of partials (nb <= 1024); also
//     writes total into rowptr[n] via the provided pointer ---
__global__ __launch_bounds__(1024) void k_bscan(int* __restrict__ bsum, int nb,
                                                int* __restrict__ total_out) {
    __shared__ int s[1024];
    int tid = threadIdx.x;
    int v = (tid < nb) ? bsum[tid] : 0;
    s[tid] = v;
    __syncthreads();
    for (int off = 1; off < 1024; off <<= 1) {
        int t = (tid >= off) ? s[tid - off] : 0;
        __syncthreads();
        s[tid] += t;
        __syncthreads();
    }
    if (tid < nb) bsum[tid] = s[tid] - v;   // exclusive
    if (tid == 1023) *total_out = s[1023];
}

// --- phase 3: block-local scan + offset; writes rowptr and scatter cursor ---
__global__ __launch_bounds__(SCAN_BLK) void k_scan_apply(int* __restrict__ cnt,
        int* __restrict__ rowptr, const int* __restrict__ bsum, int n) {
    __shared__ int s[SCAN_BLK];
    int base = blockIdx.x * SCAN_ITEMS;
    int t = threadIdx.x;
    int idx0 = base + t * 4;
    int v[4];
    int lsum = 0;
#pragma unroll
    for (int k = 0; k < 4; ++k) {
        int idx = idx0 + k;
        v[k] = (idx < n) ? cnt[idx] : 0;
        lsum += v[k];
    }
    s[t] = lsum;
    __syncthreads();
    for (int off = 1; off < SCAN_BLK; off <<= 1) {
        int tv = (t >= off) ? s[t - off] : 0;
        __syncthreads();
        s[t] += tv;
        __syncthreads();
    }
    int pre = (t ? s[t - 1] : 0) + bsum[blockIdx.x];
#pragma unroll
    for (int k = 0; k < 4; ++k) {
        int idx = idx0 + k;
        if (idx < n) { rowptr[idx] = pre; cnt[idx] = pre; }
        pre += v[k];
    }
}

// ---------------------------------------------------------------------------
// Per-edge logit -> leaky relu -> exp; lane 0 scatters (col, exp) into CSR slot.
// 16 lanes per edge.
// ---------------------------------------------------------------------------
__global__ void k_edge_scatter(const float* __restrict__ embed,
                               const int* __restrict__ kg_h, const int* __restrict__ kg_t,
                               const int* __restrict__ kg_r, const float* __restrict__ uvr,
                               int* __restrict__ next, int* __restrict__ ecol,
                               float* __restrict__ eval, int E) {
    int gid = blockIdx.x * blockDim.x + threadIdx.x;
    int e = gid >> 4;
    if (e >= E) return;
    int l = gid & 15;
    int h = kg_h[e], t = kg_t[e], r = kg_r[e];
    float4 t4 = *(const float4*)(embed + (size_t)t * DD + l * 4);
    float4 h4 = *(const float4*)(embed + (size_t)h * DD + l * 4);
    float4 u4 = *(const float4*)(uvr + r * 132 + l * 4);
    float4 v4 = *(const float4*)(uvr + r * 132 + 64 + l * 4);
    float p = t4.x * u4.x + t4.y * u4.y + t4.z * u4.z + t4.w * u4.w
            + h4.x * v4.x + h4.y * v4.y + h4.z * v4.z + h4.w * v4.w;
    p += __shfl_xor(p, 1);
    p += __shfl_xor(p, 2);
    p += __shfl_xor(p, 4);
    p += __shfl_xor(p, 8);
    if (l == 0) {
        float lg = p + uvr[r * 132 + 128];
        lg = lg >= 0.f ? lg : 0.01f * lg;
        // softmax is shift-invariant; |logit| << 1 so skip segment-max
        float exv = expf(lg);
        int pos = atomicAdd(next + h, 1);
        ecol[pos] = t;
        eval[pos] = exv;
    }
}

// wave per row: normalize eval segment to sum 1 (segment softmax denominator)
__global__ __launch_bounds__(256) void k_rowdiv(const int* __restrict__ rowptr,
                                                float* __restrict__ eval, int n) {
    int wid = (blockIdx.x * blockDim.x + threadIdx.x) >> 6;
    int lane = threadIdx.x & 63;
    if (wid >= n) return;
    int s = rowptr[wid], e = rowptr[wid + 1];
    float sum = 0.f;
    for (int i = s + lane; i < e; i += 64) sum += eval[i];
    for (int off = 32; off; off >>= 1) sum += __shfl_xor(sum, off);
    if (e > s) {
        float inv = 1.f / sum;
        for (int i = s + lane; i < e; i += 64) eval[i] *= inv;
    }
}

// CF edge scatter: 1 thread per edge
__global__ void k_scatter(const int* __restrict__ rows, const int* __restrict__ cols,
                          const float* __restrict__ vals, int* __restrict__ next,
                          int* __restrict__ ecol, float* __restrict__ eval, int E) {
    int e = blockIdx.x * blockDim.x + threadIdx.x;
    if (e >= E) return;
    int r = rows[e];
    int pos = atomicAdd(next + r, 1);
    ecol[pos] = cols[e];
    eval[pos] = vals[e];
}

// ---------------------------------------------------------------------------
// CSR SpMM, wave per row, lane = dim. One coalesced 256B store per row.
// ---------------------------------------------------------------------------
__global__ __launch_bounds__(256) void k_spmm_csr(const int* __restrict__ rowptr,
        const int* __restrict__ ecol, const float* __restrict__ eval,
        const float* __restrict__ x, float* __restrict__ out, int n) {
    int wid = (blockIdx.x * blockDim.x + threadIdx.x) >> 6;
    int lane = threadIdx.x & 63;
    if (wid >= n) return;
    int w = __builtin_amdgcn_readfirstlane(wid);   // wave-uniform -> s_load meta
    int s = rowptr[w], e = rowptr[w + 1];
    float acc0 = 0.f, acc1 = 0.f;
    int i = s;
    for (; i + 2 <= e; i += 2) {
        int c0 = ecol[i], c1 = ecol[i + 1];
        float w0 = eval[i], w1 = eval[i + 1];
        acc0 = fmaf(w0, x[(size_t)c0 * DD + lane], acc0);
        acc1 = fmaf(w1, x[(size_t)c1 * DD + lane], acc1);
    }
    if (i < e) acc0 = fmaf(eval[i], x[(size_t)ecol[i] * DD + lane], acc0);
    out[(size_t)w * DD + lane] = acc0 + acc1;
}

// ---------------------------------------------------------------------------
// Fusion gate for entity rows, wave per row, Wa/Wb staged in LDS.
// dual[i] = g*kg[i] + (1-g)*ig[i],  g = sigmoid(kg[i]@Wa + ig[i]@Wb); sums += ig
// ---------------------------------------------------------------------------
__global__ __launch_bounds__(256) void k_fusion(const float* __restrict__ kg,
        const float* __restrict__ ig, const float* __restrict__ Wa,
        const float* __restrict__ Wb, float* __restrict__ dual,
        float* __restrict__ sums, int n) {
    __shared__ float sW[2 * DD * DD];
    for (int i = threadIdx.x; i < DD * DD; i += blockDim.x) {
        sW[i] = Wa[i];
        sW[DD * DD + i] = Wb[i];
    }
    __syncthreads();
    int lane = threadIdx.x & 63;
    int wslot = (blockIdx.x * blockDim.x + threadIdx.x) >> 6;
    int nw = (gridDim.x * blockDim.x) >> 6;
    for (int row = wslot; row < n; row += nw) {
        float kv = kg[(size_t)row * DD + lane];
        float cv = ig[(size_t)row * DD + lane];
        float a = 0.f, b = 0.f;
        for (int k = 0; k < DD; ++k) {
            float kk = __shfl(kv, k);
            float ck = __shfl(cv, k);
            a = fmaf(kk, sW[k * DD + lane], a);
            b = fmaf(ck, sW[DD * DD + k * DD + lane], b);
        }
        float g = 1.f / (1.f + expf(-(a + b)));
        dual[(size_t)row * DD + lane] = g * kv + (1.f - g) * cv;
        sums[(size_t)row * DD + lane] += cv;
    }
}

// user rows: dual <- ig, sums += ig
__global__ void k_user(const float* __restrict__ ig, float* __restrict__ dual,
                       float* __restrict__ sums) {
    int i = blockIdx.x * blockDim.x + threadIdx.x;
    if (i >= N_USR * DD) return;
    size_t off = (size_t)N_ENT * DD + i;
    float v = ig[off];
    dual[off] = v;
    sums[off] += v;
}

// init: sums = dual = embed
__global__ void k_init(const float* __restrict__ embed, float* __restrict__ sums,
                       float* __restrict__ dual) {
    int i = blockIdx.x * blockDim.x + threadIdx.x;
    if (i >= N_TOT * DD) return;
    float v = embed[i];
    sums[i] = v;
    dual[i] = v;
}

// out[u,j] = sums[user_ids[u]] . sums[item_ids[j]];  8 users per block
__global__ __launch_bounds__(256) void k_out(const float* __restrict__ sums,
        const int* __restrict__ user_ids, const int* __restrict__ item_ids,
        float* __restrict__ out) {
    __shared__ float uvec[8 * DD];
    int ub = blockIdx.x * 8;  // 128 blocks
    for (int i = threadIdx.x; i < 8 * DD; i += blockDim.x) {
        int uu = i >> 6, d = i & 63;
        uvec[i] = sums[(size_t)user_ids[ub + uu] * DD + d];
    }
    __syncthreads();
    for (int j = threadIdx.x; j < 2048; j += blockDim.x) {
        const float* irow = sums + (size_t)item_ids[j] * DD;
        float acc[8] = {0.f, 0.f, 0.f, 0.f, 0.f, 0.f, 0.f, 0.f};
        for (int d = 0; d < DD; d += 4) {
            float4 iv = *(const float4*)(irow + d);
#pragma unroll
            for (int u = 0; u < 8; ++u) {
                acc[u] = fmaf(iv.x, uvec[u * DD + d + 0], acc[u]);
                acc[u] = fmaf(iv.y, uvec[u * DD + d + 1], acc[u]);
                acc[u] = fmaf(iv.z, uvec[u * DD + d + 2], acc[u]);
                acc[u] = fmaf(iv.w, uvec[u * DD + d + 3], acc[u]);
            }
        }
#pragma unroll
        for (int u = 0; u < 8; ++u) out[(size_t)(ub + u) * 2048 + j] = acc[u];
    }
}

extern "C" void kernel_launch(void* const* d_in, const int* in_sizes, int n_in,
                              void* d_out, int out_size, void* d_ws, size_t ws_size,
                              hipStream_t stream) {
    const float* embed   = (const float*)d_in[0];
    const float* rel     = (const float*)d_in[1];
    const float* Wk_w    = (const float*)d_in[2];
    const float* Wk_b    = (const float*)d_in[3];
    const float* Wa      = (const float*)d_in[4];
    const float* Wb      = (const float*)d_in[5];
    const int*   kg_h    = (const int*)d_in[6];
    const int*   kg_t    = (const int*)d_in[7];
    const int*   kg_r    = (const int*)d_in[8];
    const int*   ain_row = (const int*)d_in[9];
    const int*   ain_col = (const int*)d_in[10];
    const float* ain_val = (const float*)d_in[11];
    const int*   user_ids = (const int*)d_in[12];
    const int*   item_ids = (const int*)d_in[13];
    int E_KG = in_sizes[6];
    int E_CF = in_sizes[9];
    float* out = (float*)d_out;

    float* ws = (float*)d_ws;
    size_t off = 0;
    float* uvr       = ws + off; off += 16 * 132;
    int*   kg_cnt    = (int*)(ws + off); off += N_ENT;       // hist -> scatter cursor
    int*   cf_cnt    = (int*)(ws + off); off += N_TOT;       // adjacent: one memset
    int*   kg_rowptr = (int*)(ws + off); off += N_ENT + 4;
    int*   cf_rowptr = (int*)(ws + off); off += N_TOT + 4;
    int*   kg_bsum   = (int*)(ws + off); off += 1024;
    int*   cf_bsum   = (int*)(ws + off); off += 1024;
    int*   kg_ecol   = (int*)(ws + off); off += (size_t)E_KG;
    float* kg_eval   = ws + off; off += (size_t)E_KG;
    int*   cf_ecol   = (int*)(ws + off); off += (size_t)E_CF;
    float* cf_eval   = ws + off; off += (size_t)E_CF;
    float* bufA      = ws + off; off += (size_t)N_ENT * DD;
    float* bufB      = ws + off; off += (size_t)N_ENT * DD;
    float* dual      = ws + off; off += (size_t)N_TOT * DD;
    float* igout     = ws + off; off += (size_t)N_TOT * DD;
    float* sums      = ws + off; off += (size_t)N_TOT * DD;

    int kg_nb = (N_ENT + SCAN_ITEMS - 1) / SCAN_ITEMS;   // 98
    int cf_nb = (N_TOT + SCAN_ITEMS - 1) / SCAN_ITEMS;   // 147

    // --- CSR build for both graphs ---
    hipMemsetAsync(kg_cnt, 0, (size_t)(N_ENT + N_TOT) * sizeof(int), stream);
    hipLaunchKernelGGL(k_hist, dim3((E_KG + 255) / 256), dim3(256), 0, stream, kg_h, kg_cnt, E_KG);
    hipLaunchKernelGGL(k_hist, dim3((E_CF + 255) / 256), dim3(256), 0, stream, ain_row, cf_cnt, E_CF);
    // multi-block exclusive scans
    hipLaunchKernelGGL(k_blocksum, dim3(kg_nb), dim3(SCAN_BLK), 0, stream, kg_cnt, kg_bsum, N_ENT);
    hipLaunchKernelGGL(k_bscan, dim3(1), dim3(1024), 0, stream, kg_bsum, kg_nb, kg_rowptr + N_ENT);
    hipLaunchKernelGGL(k_scan_apply, dim3(kg_nb), dim3(SCAN_BLK), 0, stream, kg_cnt, kg_rowptr, kg_bsum, N_ENT);
    hipLaunchKernelGGL(k_blocksum, dim3(cf_nb), dim3(SCAN_BLK), 0, stream, cf_cnt, cf_bsum, N_TOT);
    hipLaunchKernelGGL(k_bscan, dim3(1), dim3(1024), 0, stream, cf_bsum, cf_nb, cf_rowptr + N_TOT);
    hipLaunchKernelGGL(k_scan_apply, dim3(cf_nb), dim3(SCAN_BLK), 0, stream, cf_cnt, cf_rowptr, cf_bsum, N_TOT);
    hipLaunchKernelGGL(k_scatter, dim3((E_CF + 255) / 256), dim3(256), 0, stream,
                       ain_row, ain_col, ain_val, cf_cnt, cf_ecol, cf_eval, E_CF);

    // --- attention (once): logits -> exp -> scatter into CSR -> row-normalize ---
    hipLaunchKernelGGL(k_rel, dim3(16), dim3(128), 0, stream, Wk_w, Wk_b, rel, uvr);
    {
        long long th = (long long)E_KG * 16;
        hipLaunchKernelGGL(k_edge_scatter, dim3((int)((th + 255) / 256)), dim3(256), 0, stream,
                           embed, kg_h, kg_t, kg_r, uvr, kg_cnt, kg_ecol, kg_eval, E_KG);
    }
    hipLaunchKernelGGL(k_rowdiv, dim3((N_ENT * 64 + 255) / 256), dim3(256), 0, stream,
                       kg_rowptr, kg_eval, N_ENT);
    hipLaunchKernelGGL(k_init, dim3((N_TOT * DD + 255) / 256), dim3(256), 0, stream,
                       embed, sums, dual);

    // --- 3 propagation layers; layer0 KG input is embed itself ---
    const float* xk = embed;
    float* kgout = bufA;
    float* kgalt = bufB;
    for (int layer = 0; layer < 3; ++layer) {
        hipLaunchKernelGGL(k_spmm_csr, dim3((N_ENT * 64 + 255) / 256), dim3(256), 0, stream,
                           kg_rowptr, kg_ecol, kg_eval, xk, kgout, N_ENT);
        hipLaunchKernelGGL(k_spmm_csr, dim3((N_TOT * 64 + 255) / 256), dim3(256), 0, stream,
                           cf_rowptr, cf_ecol, cf_eval, dual, igout, N_TOT);
        hipLaunchKernelGGL(k_fusion, dim3(2048), dim3(256), 0, stream,
                           kgout, igout, Wa, Wb, dual, sums, N_ENT);
        hipLaunchKernelGGL(k_user, dim3((N_USR * DD + 255) / 256), dim3(256), 0, stream,
                           igout, dual, sums);
        xk = kgout;
        kgout = kgalt;
        kgalt = (float*)xk;
    }

    // --- final gather-GEMM 1024 x 2048 x 64 ---
    hipLaunchKernelGGL(k_out, dim3(128), dim3(256), 0, stream, sums, user_ids, item_ids, out);
}